// Round 1
// baseline (794.021 us; speedup 1.0000x reference)
//
#include <hip/hip_runtime.h>
#include <hip/hip_bf16.h>

typedef unsigned short u16;
typedef unsigned int   u32;
typedef unsigned long long u64;
typedef __attribute__((ext_vector_type(8))) short bf16x8;   // 8 bf16 = 4 VGPRs
typedef __attribute__((ext_vector_type(4))) float f32x4;
typedef __attribute__((ext_vector_type(16))) float f32x16;

#define BB 4
#define CC 512
#define NN 4096
#define LOG2E 1.44269504f
#define KTS 520     // KtT row stride in u16 (1040B = 65*16B aligned; 260 words ≡ 4 mod 32 -> conflict-free b128)
#define PS  72      // Plds row stride in u16 (144B = 9*16B aligned; 36 words -> conflict-free b128)

static __device__ __forceinline__ u16 f2b(float f) {
    __hip_bfloat16 h = __float2bfloat16(f);
    return *(u16*)&h;
}
static __device__ __forceinline__ u16 f2b_fast(float f) {   // round-half-up bf16
    u32 u = __builtin_bit_cast(u32, f);
    return (u16)((u + 0x8000u) >> 16);
}
static __device__ __forceinline__ float b2f(u16 b) {
    u32 u = (u32)b << 16;
    return __builtin_bit_cast(float, u);
}

// async global -> LDS, 16B per lane, wave-uniform LDS base + lane*16
typedef __attribute__((address_space(1))) const u32 GU32;
typedef __attribute__((address_space(3))) u32 LU32;
__device__ __forceinline__ void async16(const void* g, void* l) {
    __builtin_amdgcn_global_load_lds((GU32*)g, (LU32*)l, 16, 0, 0);
}

// ---------------------------------------------------------------------------
// prep: 2048 blocks, each 64c x 64n tile of one batch.
//   x fp32 [B][C][N] -> XT bf16 [B][N][C], XN bf16 [B][C][N],
//   normp[cg][b][n] = partial sum_c x^2 over this block's 64 c (NO atomics)
// ---------------------------------------------------------------------------
__global__ __launch_bounds__(256) void prep_kernel(const float* __restrict__ x,
                                                   u16* __restrict__ XT,
                                                   u16* __restrict__ XN,
                                                   float* __restrict__ normp) {
    __shared__ __align__(8) u16 tile[64][68];
    __shared__ float nsum[64];
    int blk = blockIdx.x;                  // 2048 blocks
    int b  = blk >> 9;
    int r2 = blk & 511;
    int cg = r2 >> 6;                      // c-group 0..7
    int c0 = cg << 6;
    int n0 = (r2 & 63) << 6;
    int t  = threadIdx.x;
    if (t < 64) nsum[t] = 0.f;

    int nq    = t & 15;                    // float4 index along n
    int rbase = t >> 4;                    // 0..15
    float psum[4] = {0.f, 0.f, 0.f, 0.f};
    #pragma unroll
    for (int p = 0; p < 4; ++p) {
        int cl = p * 16 + rbase;           // 0..63
        const float* src = x + ((size_t)(b * CC + c0 + cl) * NN) + n0 + nq * 4;
        float4 v = *(const float4*)src;
        psum[0] += v.x * v.x; psum[1] += v.y * v.y;
        psum[2] += v.z * v.z; psum[3] += v.w * v.w;
        u64 pk = (u64)f2b(v.x) | ((u64)f2b(v.y) << 16) |
                 ((u64)f2b(v.z) << 32) | ((u64)f2b(v.w) << 48);
        *(u64*)&XN[((size_t)(b * CC + c0 + cl) * NN) + n0 + nq * 4] = pk;
        *(u64*)&tile[cl][nq * 4] = pk;
    }
    __syncthreads();                       // tile complete; nsum init visible

    // XT writes: 4 c per thread, u64 stores
    {
        int c4 = (t & 15) * 4;             // 0,4,..,60
        int nb = t >> 4;                   // 0..15
        #pragma unroll
        for (int rr = 0; rr < 4; ++rr) {
            int nl = rr * 16 + nb;
            u64 pk = (u64)tile[c4][nl] | ((u64)tile[c4 + 1][nl] << 16) |
                     ((u64)tile[c4 + 2][nl] << 32) | ((u64)tile[c4 + 3][nl] << 48);
            *(u64*)&XT[((size_t)(b * NN + n0 + nl) * CC) + c0 + c4] = pk;
        }
    }
    // norm partials via LDS atomics (block-local), then one plain store
    #pragma unroll
    for (int k = 0; k < 4; ++k) atomicAdd(&nsum[nq * 4 + k], psum[k]);
    __syncthreads();
    if (t < 64)
        normp[((size_t)cg * BB + b) * NN + n0 + t] = nsum[t];
}

// ---------------------------------------------------------------------------
// nred: norms[b][n] = sum_cg normp[cg][b][n]; maxn[b] = max_n norms.
// ---------------------------------------------------------------------------
__global__ __launch_bounds__(1024) void nred_kernel(const float* __restrict__ normp,
                                                    float* __restrict__ norms,
                                                    int* __restrict__ maxn) {
    int b = blockIdx.x;
    int t = threadIdx.x;
    float m = 0.f;
    #pragma unroll
    for (int k = 0; k < 4; ++k) {
        int n = k * 1024 + t;
        float s = 0.f;
        #pragma unroll
        for (int cg = 0; cg < 8; ++cg)
            s += normp[((size_t)cg * BB + b) * NN + n];
        norms[(size_t)b * NN + n] = s;
        m = fmaxf(m, s);
    }
    #pragma unroll
    for (int d = 1; d < 64; d <<= 1) m = fmaxf(m, __shfl_xor(m, d));
    __shared__ float wred[16];
    if ((t & 63) == 0) wred[t >> 6] = m;
    __syncthreads();
    if (t < 16) {
        float v = wred[t];
        #pragma unroll
        for (int d = 1; d < 16; d <<= 1) v = fmaxf(v, __shfl_xor(v, d));
        if (t == 0) maxn[b] = __float_as_int(v);
    }
}

// ---------------------------------------------------------------------------
// flash attention, producer/consumer waves, 256 blocks x 512 threads (1/CU).
//   waves 0-3 (G1): GEMM1 with mfma_32x32x16 (Q 32 rows x K=512 in 128 regs,
//     2x B-reuse vs 16x16x32), softmax-lite, P -> Plds (double-buffered).
//   waves 4-7 (G2): GEMM2 o^T += V P^T with 16x16x32, O in AGPRs (128c slice).
//   One __syncthreads per round; all vmem issued at round start, so the
//   barrier's vmcnt(0) drain is covered by the whole round.
//   Full j-range per block (no split, no combine pass).
// Static per-row max bound M2 = (sqrt(norm_i*max_norm)-40)*log2e (unchanged).
// ---------------------------------------------------------------------------
__global__ __launch_bounds__(512, 2) void flash_kernel(const u16* __restrict__ XT,
                                                       const u16* __restrict__ XN,
                                                       const float* __restrict__ norms,
                                                       const int* __restrict__ maxn,
                                                       float* __restrict__ outF) {
    __shared__ __align__(16) u16 KtT[2][64 * KTS];   // 133120 B
    __shared__ __align__(16) u16 Plds[2][64 * PS];   //  18432 B
    __shared__ float lLds[2][64];                    //    512 B

    int blk = blockIdx.x;                  // 256 blocks: XCD-grouped by batch
    int xcd = blk & 7;
    int b   = xcd >> 1;
    int ib  = (blk >> 3) + ((xcd & 1) << 5);   // 0..63
    int i_base = ib * 64;

    int t    = threadIdx.x;
    int w    = t >> 6;
    int lane = t & 63;
    int l31  = lane & 31;
    int h    = lane >> 5;                  // 0/1 half-wave
    int l15  = lane & 15;
    int q16  = lane >> 4;
    const int njt = NN / 64;               // 64 rounds, j advances 64/round

    const u16* xtb = XT + (size_t)b * NN * CC;
    const u16* xnb = XN + (size_t)b * CC * NN;

    bool isG1 = (w < 4);
    int ih = w & 1;                        // G1: i half (32 rows)
    int jh = (w >> 1) & 1;                 // G1: j half (32 cols)
    int cbase = (w - 4) << 7;              // G2: 128-channel slice

    // persistent per-wave state
    bf16x8 qf[32];                         // G1: Q 32 rows x 512 k (128 VGPR)
    float  M2v[16], lpart[16];             // G1: per-acc-slot bound / l partial
    f32x4  o[8][4];                        // G2: O accumulator (128 AGPR)

    if (isG1) {
        float mxn = __int_as_float(maxn[b]);
        // A-frag layout mfma_32x32x16: row = lane&31, k = kk*16 + h*8 + e
        const u16* qrow = xtb + (size_t)(i_base + ih * 32 + l31) * CC;
        #pragma unroll
        for (int kk = 0; kk < 32; ++kk)
            qf[kk] = *(const bf16x8*)(qrow + kk * 16 + h * 8);
        #pragma unroll
        for (int g = 0; g < 16; ++g) {
            int il = (g & 3) + 8 * (g >> 2) + 4 * h;   // C/D row (m74/m101)
            float nr = norms[(size_t)b * NN + i_base + ih * 32 + il];
            M2v[g] = (sqrtf(nr * mxn) - 40.f) * LOG2E;
            lpart[g] = 0.f;
        }
        // prologue: stage tile 0 into buf 0 (16 rows per G1 wave)
        const u16* src = xtb + (size_t)(w * 16) * CC + lane * 8;
        #pragma unroll
        for (int rr = 0; rr < 16; ++rr)
            async16(src + (size_t)rr * CC, &KtT[0][(w * 16 + rr) * KTS]);
    } else {
        #pragma unroll
        for (int ct = 0; ct < 8; ++ct)
            #pragma unroll
            for (int it = 0; it < 4; ++it)
                o[ct][it] = (f32x4){0.f, 0.f, 0.f, 0.f};
    }
    __syncthreads();   // drains prologue stage

    for (int r = 0; r <= njt; ++r) {
        if (isG1) {
            if (r < njt) {
                int buf = r & 1;
                // stage next K-tile into the other buffer (issued first,
                // drained by round-end barrier -> latency covered)
                if (r + 1 < njt) {
                    const u16* src = xtb + (size_t)((r + 1) * 64 + w * 16) * CC + lane * 8;
                    #pragma unroll
                    for (int rr = 0; rr < 16; ++rr)
                        async16(src + (size_t)rr * CC, &KtT[buf ^ 1][(w * 16 + rr) * KTS]);
                }
                // GEMM1: S[32i x 32j] over K=512, two independent chains
                const u16* kb = &KtT[buf][(jh * 32 + l31) * KTS + h * 8];
                f32x16 Sa, Sb;
                #pragma unroll
                for (int z = 0; z < 16; ++z) { Sa[z] = 0.f; Sb[z] = 0.f; }
                __builtin_amdgcn_s_setprio(1);
                #pragma unroll
                for (int kk = 0; kk < 16; ++kk) {
                    Sa = __builtin_amdgcn_mfma_f32_32x32x16_bf16(
                        qf[kk], *(const bf16x8*)(kb + kk * 16), Sa, 0, 0, 0);
                    Sb = __builtin_amdgcn_mfma_f32_32x32x16_bf16(
                        qf[kk + 16], *(const bf16x8*)(kb + (kk + 16) * 16), Sb, 0, 0, 0);
                }
                __builtin_amdgcn_s_setprio(0);
                // softmax-lite: p = 2^(s*log2e - M2); write P quadrant
                u16* prow = &Plds[buf][(ih * 32) * PS + jh * 32 + l31];
                #pragma unroll
                for (int g = 0; g < 16; ++g) {
                    int il = (g & 3) + 8 * (g >> 2) + 4 * h;
                    float p = __builtin_amdgcn_exp2f(fmaf(Sa[g] + Sb[g], LOG2E, -M2v[g]));
                    u16 hb = f2b_fast(p);
                    lpart[g] += b2f(hb);       // l consistent with bf16 P
                    prow[il * PS] = hb;
                }
            } else {
                // r == njt: reduce l over the 32 j-lanes, publish per jh half
                #pragma unroll
                for (int g = 0; g < 16; ++g) {
                    float s = lpart[g];
                    s += __shfl_xor(s, 1);  s += __shfl_xor(s, 2);
                    s += __shfl_xor(s, 4);  s += __shfl_xor(s, 8);
                    s += __shfl_xor(s, 16);
                    lpart[g] = s;
                }
                if (l31 == 0) {
                    #pragma unroll
                    for (int g = 0; g < 16; ++g) {
                        int il = (g & 3) + 8 * (g >> 2) + 4 * h;
                        lLds[jh][ih * 32 + il] = lpart[g];
                    }
                }
            }
        } else {
            if (r > 0) {
                int q  = r - 1;            // consume P[q] written last round
                int p2 = q & 1;
                int j0 = q * 64;
                #pragma unroll
                for (int js = 0; js < 2; ++js) {
                    bf16x8 vf[8];
                    #pragma unroll
                    for (int ct = 0; ct < 8; ++ct)
                        vf[ct] = *(const bf16x8*)(xnb +
                            (size_t)(cbase + ct * 16 + l15) * NN + j0 + js * 32 + q16 * 8);
                    bf16x8 pb[4];
                    #pragma unroll
                    for (int it = 0; it < 4; ++it)
                        pb[it] = *(const bf16x8*)&Plds[p2][(it * 16 + l15) * PS + js * 32 + q16 * 8];
                    __builtin_amdgcn_s_setprio(1);
                    #pragma unroll
                    for (int ct = 0; ct < 8; ++ct)
                        #pragma unroll
                        for (int it = 0; it < 4; ++it)
                            o[ct][it] = __builtin_amdgcn_mfma_f32_16x16x32_bf16(
                                vf[ct], pb[it], o[ct][it], 0, 0, 0);
                    __builtin_amdgcn_s_setprio(0);
                }
            }
        }
        __syncthreads();
    }

    // epilogue: G2 waves normalize + store their 128-channel slice
    if (!isG1) {
        float linv[4];
        #pragma unroll
        for (int it = 0; it < 4; ++it)
            linv[it] = 1.f / (lLds[0][it * 16 + l15] + lLds[1][it * 16 + l15]);
        float* ob = outF + (size_t)b * CC * NN;
        #pragma unroll
        for (int ct = 0; ct < 8; ++ct)
            #pragma unroll
            for (int rr = 0; rr < 4; ++rr) {
                int c = cbase + ct * 16 + q16 * 4 + rr;
                float* orow = ob + (size_t)c * NN + i_base;
                #pragma unroll
                for (int it = 0; it < 4; ++it)
                    orow[it * 16 + l15] = o[ct][it][rr] * linv[it];
            }
    }
}

extern "C" void kernel_launch(void* const* d_in, const int* in_sizes, int n_in,
                              void* d_out, int out_size, void* d_ws, size_t ws_size,
                              hipStream_t stream) {
    const float* x = (const float*)d_in[0];
    size_t SZ = (size_t)BB * NN * CC;          // elements
    size_t BN = (size_t)BB * NN;
    u16* XT = (u16*)d_ws;
    u16* XN = XT + SZ;
    float* norms = (float*)(XN + SZ);
    float* normp = norms + BN;                 // 8 * B * N floats
    int*   maxn  = (int*)(normp + 8 * BN);
    float* out = (float*)d_out;

    prep_kernel<<<2048, 256, 0, stream>>>(x, XT, XN, normp);
    nred_kernel<<<BB, 1024, 0, stream>>>(normp, norms, maxn);
    flash_kernel<<<256, 512, 0, stream>>>(XT, XN, norms, maxn, out);
}

// Round 2
// 703.319 us; speedup vs baseline: 1.1290x; 1.1290x over previous
//
#include <hip/hip_runtime.h>
#include <hip/hip_bf16.h>

typedef unsigned short u16;
typedef unsigned int   u32;
typedef unsigned long long u64;
typedef __attribute__((ext_vector_type(8))) short bf16x8;  // 8 bf16 = 4 VGPRs
typedef __attribute__((ext_vector_type(4))) float f32x4;

#define BB 4
#define CC 512
#define NN 4096
#define LOG2E 1.44269504f

static __device__ __forceinline__ u16 f2b(float f) {
    __hip_bfloat16 h = __float2bfloat16(f);
    return *(u16*)&h;
}
static __device__ __forceinline__ u16 f2b_fast(float f) {   // round-half-up bf16
    u32 u = __builtin_bit_cast(u32, f);
    return (u16)((u + 0x8000u) >> 16);
}
static __device__ __forceinline__ float b2f(u16 b) {
    u32 u = (u32)b << 16;
    return __builtin_bit_cast(float, u);
}

// ---------------------------------------------------------------------------
// prep: 2048 blocks, each 64c x 64n tile of one batch.
//   x fp32 [B][C][N] -> XT bf16 [B][N][C], XN bf16 [B][C][N],
//   normp[cg][b][n] = partial sum_c x^2 over this block's 64 c (NO atomics)
// ---------------------------------------------------------------------------
__global__ __launch_bounds__(256) void prep_kernel(const float* __restrict__ x,
                                                   u16* __restrict__ XT,
                                                   u16* __restrict__ XN,
                                                   float* __restrict__ normp) {
    __shared__ __align__(8) u16 tile[64][68];
    __shared__ float nsum[64];
    int blk = blockIdx.x;                  // 2048 blocks
    int b  = blk >> 9;
    int r2 = blk & 511;
    int cg = r2 >> 6;                      // c-group 0..7
    int c0 = cg << 6;
    int n0 = (r2 & 63) << 6;
    int t  = threadIdx.x;
    if (t < 64) nsum[t] = 0.f;

    int nq    = t & 15;                    // float4 index along n
    int rbase = t >> 4;                    // 0..15
    float psum[4] = {0.f, 0.f, 0.f, 0.f};
    #pragma unroll
    for (int p = 0; p < 4; ++p) {
        int cl = p * 16 + rbase;           // 0..63
        const float* src = x + ((size_t)(b * CC + c0 + cl) * NN) + n0 + nq * 4;
        float4 v = *(const float4*)src;
        psum[0] += v.x * v.x; psum[1] += v.y * v.y;
        psum[2] += v.z * v.z; psum[3] += v.w * v.w;
        u64 pk = (u64)f2b(v.x) | ((u64)f2b(v.y) << 16) |
                 ((u64)f2b(v.z) << 32) | ((u64)f2b(v.w) << 48);
        *(u64*)&XN[((size_t)(b * CC + c0 + cl) * NN) + n0 + nq * 4] = pk;
        *(u64*)&tile[cl][nq * 4] = pk;
    }
    __syncthreads();                       // tile complete; nsum init visible

    // XT writes: 4 c per thread, u64 stores
    {
        int c4 = (t & 15) * 4;             // 0,4,..,60
        int nb = t >> 4;                   // 0..15
        #pragma unroll
        for (int rr = 0; rr < 4; ++rr) {
            int nl = rr * 16 + nb;
            u64 pk = (u64)tile[c4][nl] | ((u64)tile[c4 + 1][nl] << 16) |
                     ((u64)tile[c4 + 2][nl] << 32) | ((u64)tile[c4 + 3][nl] << 48);
            *(u64*)&XT[((size_t)(b * NN + n0 + nl) * CC) + c0 + c4] = pk;
        }
    }
    // norm partials via LDS atomics (block-local), then one plain store
    #pragma unroll
    for (int k = 0; k < 4; ++k) atomicAdd(&nsum[nq * 4 + k], psum[k]);
    __syncthreads();
    if (t < 64)
        normp[((size_t)cg * BB + b) * NN + n0 + t] = nsum[t];
}

// ---------------------------------------------------------------------------
// nred: norms[b][n] = sum_cg normp[cg][b][n]; maxn[b] = max_n norms.
// 4 blocks (one per batch) x 1024 threads; no atomics, no memset needed.
// ---------------------------------------------------------------------------
__global__ __launch_bounds__(1024) void nred_kernel(const float* __restrict__ normp,
                                                    float* __restrict__ norms,
                                                    int* __restrict__ maxn) {
    int b = blockIdx.x;
    int t = threadIdx.x;
    float m = 0.f;
    #pragma unroll
    for (int k = 0; k < 4; ++k) {
        int n = k * 1024 + t;
        float s = 0.f;
        #pragma unroll
        for (int cg = 0; cg < 8; ++cg)
            s += normp[((size_t)cg * BB + b) * NN + n];
        norms[(size_t)b * NN + n] = s;
        m = fmaxf(m, s);
    }
    #pragma unroll
    for (int d = 1; d < 64; d <<= 1) m = fmaxf(m, __shfl_xor(m, d));
    __shared__ float wred[16];
    if ((t & 63) == 0) wred[t >> 6] = m;
    __syncthreads();
    if (t < 16) {
        float v = wred[t];
        #pragma unroll
        for (int d = 1; d < 16; d <<= 1) v = fmaxf(v, __shfl_xor(v, d));
        if (t == 0) maxn[b] = __float_as_int(v);
    }
}

// ---------------------------------------------------------------------------
// flash attention, static per-row max bound. R0 structure (proven 210 us)
// with ONE change: GEMM1's K fragments load DIRECTLY from global XT instead
// of LDS-staged KtT. R0 was LDS-read-pipe bound (288 ds_read_b128/CU/iter
// at ~12cy + ~4cy conflict each ~= 5500cy vs 2500cy MFMA); the staged tile
// was a verbatim copy of XT rows, re-read 8x per CU while L1/L2 hold it.
// Removing the staging deletes 256 of 288 LDS reads, all async16 traffic,
// and the vmcnt drain at the barrier. Everything else byte-identical:
// per-iter j0-relative addresses (R5: do NOT hoist across iterations),
// no extra live loop state (R4: 256 reg/wave cliff).
// ---------------------------------------------------------------------------
__global__ __launch_bounds__(256, 2) void flash_kernel(const u16* __restrict__ XT,
                                                       const u16* __restrict__ XN,
                                                       const float* __restrict__ norms,
                                                       const int* __restrict__ maxn,
                                                       float* __restrict__ outF,
                                                       u16* __restrict__ outH,
                                                       float* __restrict__ l0g,
                                                       float* __restrict__ l1g,
                                                       int split) {
    __shared__ __align__(16) u16 Plds[2][64 * 40];
    __shared__ float lLds[64];

    int blk   = blockIdx.x;
    int inner = blk & 255;
    int hf    = split ? (blk >> 8) : 0;
    int xcd = inner & 7;
    int b   = xcd >> 1;
    int ib  = (inner >> 3) + ((xcd & 1) << 5);
    int i_base = ib * 64;
    int jlo = hf * (NN / 2) * split;
    int njt = split ? 64 : 128;

    int t    = threadIdx.x;
    int w    = t >> 6;
    int lane = t & 63;
    int l15  = lane & 15;
    int q    = lane >> 4;

    const u16* xtb = XT + (size_t)b * NN * CC;
    const u16* xnb = XN + (size_t)b * CC * NN;

    float mxn = __int_as_float(maxn[b]);
    float M2[4];
    #pragma unroll
    for (int r = 0; r < 4; ++r) {
        float nr = norms[(size_t)b * NN + i_base + w * 16 + q * 4 + r];
        M2[r] = (sqrtf(nr * mxn) - 40.f) * LOG2E;
    }

    // Q fragments: rows i_base + w*16 + l15, all 512 c
    bf16x8 qf[16];
    {
        const u16* qrow = xtb + (size_t)(i_base + w * 16 + l15) * CC;
        #pragma unroll
        for (int kk = 0; kk < 16; ++kk)
            qf[kk] = *(const bf16x8*)(qrow + kk * 32 + q * 8);
    }

    f32x4 o[8][4];
    #pragma unroll
    for (int ct = 0; ct < 8; ++ct)
        #pragma unroll
        for (int it = 0; it < 4; ++it)
            o[ct][it] = (f32x4){0.f, 0.f, 0.f, 0.f};
    float lpart[4] = {0.f, 0.f, 0.f, 0.f};

    __syncthreads();   // align waves at loop entry (lockstep helps L1/L2 reuse)

    for (int jt = 0; jt < njt; ++jt) {
        int buf = jt & 1;
        int j0  = jlo + jt * 32;

        // V fragments for THIS iter (consumed by GEMM2 after the barrier)
        bf16x8 vf[8];
        #pragma unroll
        for (int ct = 0; ct < 8; ++ct)
            vf[ct] = *(const bf16x8*)(xnb + (size_t)(w * 128 + ct * 16 + l15) * NN + j0 + q * 8);

        // GEMM1: S[16 rows][32 j]; K fragments straight from XT (L1/L2-hot:
        // same 32KB tile is read by all waves of the CU in lockstep).
        // Address map identical to the old staged KtT[r][c] = XT[j0+r][c].
        const u16* k0 = xtb + (size_t)(j0 + l15) * CC + q * 8;
        f32x4 s0 = {0.f,0.f,0.f,0.f}, s1 = {0.f,0.f,0.f,0.f};
        #pragma unroll
        for (int kk = 0; kk < 16; ++kk) {
            bf16x8 b0 = *(const bf16x8*)(k0 + kk * 32);
            bf16x8 b1 = *(const bf16x8*)(k0 + (size_t)16 * CC + kk * 32);
            s0 = __builtin_amdgcn_mfma_f32_16x16x32_bf16(qf[kk], b0, s0, 0, 0, 0);
            s1 = __builtin_amdgcn_mfma_f32_16x16x32_bf16(qf[kk], b1, s1, 0, 0, 0);
        }

        // softmax-lite: p = 2^(s*log2e - M2); no shuffles, no rescale
        #pragma unroll
        for (int r = 0; r < 4; ++r) {
            float p0 = __builtin_amdgcn_exp2f(fmaf(s0[r], LOG2E, -M2[r]));
            float p1 = __builtin_amdgcn_exp2f(fmaf(s1[r], LOG2E, -M2[r]));
            u16 h0 = f2b_fast(p0), h1 = f2b_fast(p1);
            lpart[r] += b2f(h0) + b2f(h1);       // l consistent with bf16 P
            int row = w * 16 + q * 4 + r;
            Plds[buf][row * 40 +      l15] = h0;
            Plds[buf][row * 40 + 16 + l15] = h1;
        }
        __syncthreads();   // P ready (vf long since landed)

        // GEMM2: O^T += V P^T
        bf16x8 pb[4];
        #pragma unroll
        for (int it = 0; it < 4; ++it)
            pb[it] = *(const bf16x8*)&Plds[buf][(it * 16 + l15) * 40 + q * 8];
        #pragma unroll
        for (int ct = 0; ct < 8; ++ct)
            #pragma unroll
            for (int it = 0; it < 4; ++it)
                o[ct][it] = __builtin_amdgcn_mfma_f32_16x16x32_bf16(vf[ct], pb[it], o[ct][it], 0, 0, 0);
    }

    // reduce l over the 16 column-lanes (once)
    #pragma unroll
    for (int r = 0; r < 4; ++r) {
        float s = lpart[r];
        s += __shfl_xor(s, 1);
        s += __shfl_xor(s, 2);
        s += __shfl_xor(s, 4);
        s += __shfl_xor(s, 8);
        lpart[r] = s;
    }

    if (!split) {
        if (l15 == 0) {
            #pragma unroll
            for (int r = 0; r < 4; ++r) lLds[w * 16 + q * 4 + r] = lpart[r];
        }
        __syncthreads();
        float linv[4];
        #pragma unroll
        for (int it = 0; it < 4; ++it) linv[it] = 1.f / lLds[it * 16 + l15];
        float* ob = outF + (size_t)b * CC * NN;
        #pragma unroll
        for (int ct = 0; ct < 8; ++ct)
            #pragma unroll
            for (int r = 0; r < 4; ++r) {
                int c = w * 128 + ct * 16 + q * 4 + r;
                float* orow = ob + (size_t)c * NN + i_base;
                #pragma unroll
                for (int it = 0; it < 4; ++it)
                    orow[it * 16 + l15] = o[ct][it][r] * linv[it];
            }
    } else {
        if (l15 == 0) {
            float* lg = (hf == 0) ? l0g : l1g;
            #pragma unroll
            for (int r = 0; r < 4; ++r)
                lg[(size_t)b * NN + i_base + w * 16 + q * 4 + r] = lpart[r];
        }
        if (hf == 0) {
            float* ob = outF + (size_t)b * CC * NN;
            #pragma unroll
            for (int ct = 0; ct < 8; ++ct)
                #pragma unroll
                for (int r = 0; r < 4; ++r) {
                    int c = w * 128 + ct * 16 + q * 4 + r;
                    float* orow = ob + (size_t)c * NN + i_base;
                    #pragma unroll
                    for (int it = 0; it < 4; ++it)
                        orow[it * 16 + l15] = o[ct][it][r];       // unnormalized
                }
        } else {
            u16* ob = outH + (size_t)b * CC * NN;
            #pragma unroll
            for (int ct = 0; ct < 8; ++ct)
                #pragma unroll
                for (int r = 0; r < 4; ++r) {
                    int c = w * 128 + ct * 16 + q * 4 + r;
                    u16* orow = ob + (size_t)c * NN + i_base;
                    #pragma unroll
                    for (int it = 0; it < 4; ++it)
                        orow[it * 16 + l15] = f2b(o[ct][it][r]);
                }
        }
    }
}

// combine: out = (O0 + O1) / (l0 + l1)   (same static M across splits)
__global__ __launch_bounds__(256) void combine_kernel(float* __restrict__ out,
                                                      const u16* __restrict__ P1,
                                                      const float* __restrict__ l0,
                                                      const float* __restrict__ l1) {
    size_t g = (size_t)blockIdx.x * 256 + threadIdx.x;
    size_t f = g * 4;
    int i = (int)(f & (NN - 1));
    int b = (int)(f >> 21);
    float4 p0 = *(float4*)&out[f];
    u64 pk = *(const u64*)&P1[f];
    float p0a[4] = {p0.x, p0.y, p0.z, p0.w};
    float r[4];
    #pragma unroll
    for (int k = 0; k < 4; ++k) {
        float l = l0[(size_t)b * NN + i + k] + l1[(size_t)b * NN + i + k];
        float p1f = b2f((u16)((pk >> (16 * k)) & 0xFFFFu));
        r[k] = (p0a[k] + p1f) / l;
    }
    *(float4*)&out[f] = (float4){r[0], r[1], r[2], r[3]};
}

extern "C" void kernel_launch(void* const* d_in, const int* in_sizes, int n_in,
                              void* d_out, int out_size, void* d_ws, size_t ws_size,
                              hipStream_t stream) {
    const float* x = (const float*)d_in[0];
    size_t SZ = (size_t)BB * NN * CC;          // elements
    size_t BN = (size_t)BB * NN;
    u16* XT = (u16*)d_ws;
    u16* XN = XT + SZ;
    u16* P1 = XN + SZ;
    float* norms = (float*)(P1 + SZ);
    float* l0g   = norms + BN;
    float* l1g   = l0g + BN;
    float* normp = l1g + BN;                   // 8 * B * N floats
    int*   maxn  = (int*)(normp + 8 * BN);
    size_t needed = 3 * SZ * 2 + 3 * BN * 4 + 8 * BN * 4 + 64;
    int split = (ws_size >= needed) ? 1 : 0;
    float* out = (float*)d_out;
    if (!split) {   // fallback layout without P1
        norms = (float*)(XN + SZ);
        l0g = norms + BN;
        l1g = l0g;
        normp = l1g + BN;
        maxn = (int*)(normp + 8 * BN);
    }

    prep_kernel<<<2048, 256, 0, stream>>>(x, XT, XN, normp);
    nred_kernel<<<BB, 1024, 0, stream>>>(normp, norms, maxn);
    if (split) {
        flash_kernel<<<512, 256, 0, stream>>>(XT, XN, norms, maxn, out, P1, l0g, l1g, 1);
        combine_kernel<<<(BB * CC * NN / 4) / 256, 256, 0, stream>>>(out, P1, l0g, l1g);
    } else {
        flash_kernel<<<256, 256, 0, stream>>>(XT, XN, norms, maxn, out, P1, l0g, l1g, 0);
    }
}

// Round 3
// 311.259 us; speedup vs baseline: 2.5510x; 2.2596x over previous
//
#include <hip/hip_runtime.h>
#include <hip/hip_bf16.h>

typedef unsigned short u16;
typedef unsigned int   u32;
typedef unsigned long long u64;
typedef __attribute__((ext_vector_type(8))) short bf16x8;  // 8 bf16 = 4 VGPRs
typedef __attribute__((ext_vector_type(4))) float f32x4;

#define BB 4
#define CC 512
#define NN 4096
#define LOG2E 1.44269504f

static __device__ __forceinline__ u16 f2b(float f) {
    __hip_bfloat16 h = __float2bfloat16(f);
    return *(u16*)&h;
}
static __device__ __forceinline__ u16 f2b_fast(float f) {   // round-half-up bf16
    u32 u = __builtin_bit_cast(u32, f);
    return (u16)((u + 0x8000u) >> 16);
}
static __device__ __forceinline__ float b2f(u16 b) {
    u32 u = (u32)b << 16;
    return __builtin_bit_cast(float, u);
}

// async global -> LDS, 16B per lane, wave-uniform LDS base + lane*16
typedef __attribute__((address_space(1))) const u32 GU32;
typedef __attribute__((address_space(3))) u32 LU32;
__device__ __forceinline__ void async16(const void* g, void* l) {
    __builtin_amdgcn_global_load_lds((GU32*)g, (LU32*)l, 16, 0, 0);
}

// ---------------------------------------------------------------------------
// prep: 2048 blocks, each 64c x 64n tile of one batch.
//   x fp32 [B][C][N] -> XT bf16 [B][N][C], XN bf16 [B][C][N],
//   normp[cg][b][n] = partial sum_c x^2 over this block's 64 c (NO atomics)
// ---------------------------------------------------------------------------
__global__ __launch_bounds__(256) void prep_kernel(const float* __restrict__ x,
                                                   u16* __restrict__ XT,
                                                   u16* __restrict__ XN,
                                                   float* __restrict__ normp) {
    __shared__ __align__(8) u16 tile[64][68];
    __shared__ float nsum[64];
    int blk = blockIdx.x;                  // 2048 blocks
    int b  = blk >> 9;
    int r2 = blk & 511;
    int cg = r2 >> 6;                      // c-group 0..7
    int c0 = cg << 6;
    int n0 = (r2 & 63) << 6;
    int t  = threadIdx.x;
    if (t < 64) nsum[t] = 0.f;

    int nq    = t & 15;                    // float4 index along n
    int rbase = t >> 4;                    // 0..15
    float psum[4] = {0.f, 0.f, 0.f, 0.f};
    #pragma unroll
    for (int p = 0; p < 4; ++p) {
        int cl = p * 16 + rbase;           // 0..63
        const float* src = x + ((size_t)(b * CC + c0 + cl) * NN) + n0 + nq * 4;
        float4 v = *(const float4*)src;
        psum[0] += v.x * v.x; psum[1] += v.y * v.y;
        psum[2] += v.z * v.z; psum[3] += v.w * v.w;
        u64 pk = (u64)f2b(v.x) | ((u64)f2b(v.y) << 16) |
                 ((u64)f2b(v.z) << 32) | ((u64)f2b(v.w) << 48);
        *(u64*)&XN[((size_t)(b * CC + c0 + cl) * NN) + n0 + nq * 4] = pk;
        *(u64*)&tile[cl][nq * 4] = pk;
    }
    __syncthreads();                       // tile complete; nsum init visible

    // XT writes: 4 c per thread, u64 stores
    {
        int c4 = (t & 15) * 4;             // 0,4,..,60
        int nb = t >> 4;                   // 0..15
        #pragma unroll
        for (int rr = 0; rr < 4; ++rr) {
            int nl = rr * 16 + nb;
            u64 pk = (u64)tile[c4][nl] | ((u64)tile[c4 + 1][nl] << 16) |
                     ((u64)tile[c4 + 2][nl] << 32) | ((u64)tile[c4 + 3][nl] << 48);
            *(u64*)&XT[((size_t)(b * NN + n0 + nl) * CC) + c0 + c4] = pk;
        }
    }
    // norm partials via LDS atomics (block-local), then one plain store
    #pragma unroll
    for (int k = 0; k < 4; ++k) atomicAdd(&nsum[nq * 4 + k], psum[k]);
    __syncthreads();
    if (t < 64)
        normp[((size_t)cg * BB + b) * NN + n0 + t] = nsum[t];
}

// ---------------------------------------------------------------------------
// nred: norms[b][n] = sum_cg normp[cg][b][n]; maxn[b] = max_n norms.
// 4 blocks (one per batch) x 1024 threads; no atomics, no memset needed.
// ---------------------------------------------------------------------------
__global__ __launch_bounds__(1024) void nred_kernel(const float* __restrict__ normp,
                                                    float* __restrict__ norms,
                                                    int* __restrict__ maxn) {
    int b = blockIdx.x;
    int t = threadIdx.x;
    float m = 0.f;
    #pragma unroll
    for (int k = 0; k < 4; ++k) {
        int n = k * 1024 + t;
        float s = 0.f;
        #pragma unroll
        for (int cg = 0; cg < 8; ++cg)
            s += normp[((size_t)cg * BB + b) * NN + n];
        norms[(size_t)b * NN + n] = s;
        m = fmaxf(m, s);
    }
    #pragma unroll
    for (int d = 1; d < 64; d <<= 1) m = fmaxf(m, __shfl_xor(m, d));
    __shared__ float wred[16];
    if ((t & 63) == 0) wred[t >> 6] = m;
    __syncthreads();
    if (t < 16) {
        float v = wred[t];
        #pragma unroll
        for (int d = 1; d < 16; d <<= 1) v = fmaxf(v, __shfl_xor(v, d));
        if (t == 0) maxn[b] = __float_as_int(v);
    }
}

// ---------------------------------------------------------------------------
// flash attention, static per-row max bound. EXACT R0/210us loop body restored
// (R2 proved K-from-global is latency-poison: 627us; R1 proved role-split
// thrashes L2: 723us). Two additive tweaks only:
//   (1) async16 stage issued BEFORE vf loads (more latency cover pre-barrier)
//   (2) s_setprio(1) around both MFMA clusters (T5; 2 indep blocks/CU =
//       m191 phase-diverse case)
// Do NOT hoist pointers across iterations; do NOT add live loop state
// (256 reg/wave cliff: o=128 AGPR + qf 64 + vf 32 + s 8 + addr).
// ---------------------------------------------------------------------------
__global__ __launch_bounds__(256, 2) void flash_kernel(const u16* __restrict__ XT,
                                                       const u16* __restrict__ XN,
                                                       const float* __restrict__ norms,
                                                       const int* __restrict__ maxn,
                                                       float* __restrict__ outF,
                                                       u16* __restrict__ outH,
                                                       float* __restrict__ l0g,
                                                       float* __restrict__ l1g,
                                                       int split) {
    __shared__ __align__(16) u16 KtT[2][32 * 520];        // [j][c], stride 520
    __shared__ __align__(16) u16 Plds[2][64 * 40];
    __shared__ float lLds[64];

    int blk   = blockIdx.x;
    int inner = blk & 255;
    int hf    = split ? (blk >> 8) : 0;
    int xcd = inner & 7;
    int b   = xcd >> 1;
    int ib  = (inner >> 3) + ((xcd & 1) << 5);
    int i_base = ib * 64;
    int jlo = hf * (NN / 2) * split;
    int njt = split ? 64 : 128;

    int t    = threadIdx.x;
    int w    = t >> 6;
    int lane = t & 63;
    int l15  = lane & 15;
    int q    = lane >> 4;

    const u16* xtb = XT + (size_t)b * NN * CC;
    const u16* xnb = XN + (size_t)b * CC * NN;

    float mxn = __int_as_float(maxn[b]);
    float M2[4];
    #pragma unroll
    for (int r = 0; r < 4; ++r) {
        float nr = norms[(size_t)b * NN + i_base + w * 16 + q * 4 + r];
        M2[r] = (sqrtf(nr * mxn) - 40.f) * LOG2E;
    }

    // Q fragments: rows i_base + w*16 + l15, all 512 c
    bf16x8 qf[16];
    {
        const u16* qrow = xtb + (size_t)(i_base + w * 16 + l15) * CC;
        #pragma unroll
        for (int kk = 0; kk < 16; ++kk)
            qf[kk] = *(const bf16x8*)(qrow + kk * 32 + q * 8);
    }

    f32x4 o[8][4];
    #pragma unroll
    for (int ct = 0; ct < 8; ++ct)
        #pragma unroll
        for (int it = 0; it < 4; ++it)
            o[ct][it] = (f32x4){0.f, 0.f, 0.f, 0.f};
    float lpart[4] = {0.f, 0.f, 0.f, 0.f};

    // prologue: stage tile 0
    {
        const u16* src = xtb + (size_t)(jlo + w * 8) * CC + lane * 8;
        #pragma unroll
        for (int rr = 0; rr < 8; ++rr)
            async16(src + rr * CC, &KtT[0][(w * 8 + rr) * 520]);
    }
    __syncthreads();

    for (int jt = 0; jt < njt; ++jt) {
        int buf = jt & 1;
        int j0  = jlo + jt * 32;

        // stage NEXT K-tile into the other buffer (issued first: maximal
        // latency cover before the barrier's vmcnt drain)
        if (jt + 1 < njt) {
            const u16* src = xtb + (size_t)(j0 + 32 + w * 8) * CC + lane * 8;
            #pragma unroll
            for (int rr = 0; rr < 8; ++rr)
                async16(src + rr * CC, &KtT[buf ^ 1][(w * 8 + rr) * 520]);
        }

        // V fragments for THIS iter (drained at the barrier below)
        bf16x8 vf[8];
        #pragma unroll
        for (int ct = 0; ct < 8; ++ct)
            vf[ct] = *(const bf16x8*)(xnb + (size_t)(w * 128 + ct * 16 + l15) * NN + j0 + q * 8);

        // GEMM1: S[16 rows][32 j] from KtT[buf]  (2 chains — do not widen)
        f32x4 s0 = {0.f,0.f,0.f,0.f}, s1 = {0.f,0.f,0.f,0.f};
        __builtin_amdgcn_s_setprio(1);
        #pragma unroll
        for (int kk = 0; kk < 16; ++kk) {
            bf16x8 b0 = *(const bf16x8*)&KtT[buf][(l15)      * 520 + kk * 32 + q * 8];
            bf16x8 b1 = *(const bf16x8*)&KtT[buf][(16 + l15) * 520 + kk * 32 + q * 8];
            s0 = __builtin_amdgcn_mfma_f32_16x16x32_bf16(qf[kk], b0, s0, 0, 0, 0);
            s1 = __builtin_amdgcn_mfma_f32_16x16x32_bf16(qf[kk], b1, s1, 0, 0, 0);
        }
        __builtin_amdgcn_s_setprio(0);

        // softmax-lite: p = 2^(s*log2e - M2); no shuffles, no rescale
        #pragma unroll
        for (int r = 0; r < 4; ++r) {
            float p0 = __builtin_amdgcn_exp2f(fmaf(s0[r], LOG2E, -M2[r]));
            float p1 = __builtin_amdgcn_exp2f(fmaf(s1[r], LOG2E, -M2[r]));
            u16 h0 = f2b_fast(p0), h1 = f2b_fast(p1);
            lpart[r] += b2f(h0) + b2f(h1);       // l consistent with bf16 P
            int row = w * 16 + q * 4 + r;
            Plds[buf][row * 40 +      l15] = h0;
            Plds[buf][row * 40 + 16 + l15] = h1;
        }
        __syncthreads();   // drains vf + stage(i+1); P ready

        // GEMM2: O^T += V P^T
        bf16x8 pb[4];
        #pragma unroll
        for (int it = 0; it < 4; ++it)
            pb[it] = *(const bf16x8*)&Plds[buf][(it * 16 + l15) * 40 + q * 8];
        __builtin_amdgcn_s_setprio(1);
        #pragma unroll
        for (int ct = 0; ct < 8; ++ct)
            #pragma unroll
            for (int it = 0; it < 4; ++it)
                o[ct][it] = __builtin_amdgcn_mfma_f32_16x16x32_bf16(vf[ct], pb[it], o[ct][it], 0, 0, 0);
        __builtin_amdgcn_s_setprio(0);
    }

    // reduce l over the 16 column-lanes (once)
    #pragma unroll
    for (int r = 0; r < 4; ++r) {
        float s = lpart[r];
        s += __shfl_xor(s, 1);
        s += __shfl_xor(s, 2);
        s += __shfl_xor(s, 4);
        s += __shfl_xor(s, 8);
        lpart[r] = s;
    }

    if (!split) {
        if (l15 == 0) {
            #pragma unroll
            for (int r = 0; r < 4; ++r) lLds[w * 16 + q * 4 + r] = lpart[r];
        }
        __syncthreads();
        float linv[4];
        #pragma unroll
        for (int it = 0; it < 4; ++it) linv[it] = 1.f / lLds[it * 16 + l15];
        float* ob = outF + (size_t)b * CC * NN;
        #pragma unroll
        for (int ct = 0; ct < 8; ++ct)
            #pragma unroll
            for (int r = 0; r < 4; ++r) {
                int c = w * 128 + ct * 16 + q * 4 + r;
                float* orow = ob + (size_t)c * NN + i_base;
                #pragma unroll
                for (int it = 0; it < 4; ++it)
                    orow[it * 16 + l15] = o[ct][it][r] * linv[it];
            }
    } else {
        if (l15 == 0) {
            float* lg = (hf == 0) ? l0g : l1g;
            #pragma unroll
            for (int r = 0; r < 4; ++r)
                lg[(size_t)b * NN + i_base + w * 16 + q * 4 + r] = lpart[r];
        }
        if (hf == 0) {
            float* ob = outF + (size_t)b * CC * NN;
            #pragma unroll
            for (int ct = 0; ct < 8; ++ct)
                #pragma unroll
                for (int r = 0; r < 4; ++r) {
                    int c = w * 128 + ct * 16 + q * 4 + r;
                    float* orow = ob + (size_t)c * NN + i_base;
                    #pragma unroll
                    for (int it = 0; it < 4; ++it)
                        orow[it * 16 + l15] = o[ct][it][r];       // unnormalized
                }
        } else {
            u16* ob = outH + (size_t)b * CC * NN;
            #pragma unroll
            for (int ct = 0; ct < 8; ++ct)
                #pragma unroll
                for (int r = 0; r < 4; ++r) {
                    int c = w * 128 + ct * 16 + q * 4 + r;
                    u16* orow = ob + (size_t)c * NN + i_base;
                    #pragma unroll
                    for (int it = 0; it < 4; ++it)
                        orow[it * 16 + l15] = f2b(o[ct][it][r]);
                }
        }
    }
}

// combine: out = (O0 + O1) / (l0 + l1)   (same static M across splits)
__global__ __launch_bounds__(256) void combine_kernel(float* __restrict__ out,
                                                      const u16* __restrict__ P1,
                                                      const float* __restrict__ l0,
                                                      const float* __restrict__ l1) {
    size_t g = (size_t)blockIdx.x * 256 + threadIdx.x;
    size_t f = g * 4;
    int i = (int)(f & (NN - 1));
    int b = (int)(f >> 21);
    float4 p0 = *(float4*)&out[f];
    u64 pk = *(const u64*)&P1[f];
    float p0a[4] = {p0.x, p0.y, p0.z, p0.w};
    float r[4];
    #pragma unroll
    for (int k = 0; k < 4; ++k) {
        float l = l0[(size_t)b * NN + i + k] + l1[(size_t)b * NN + i + k];
        float p1f = b2f((u16)((pk >> (16 * k)) & 0xFFFFu));
        r[k] = (p0a[k] + p1f) / l;
    }
    *(float4*)&out[f] = (float4){r[0], r[1], r[2], r[3]};
}

extern "C" void kernel_launch(void* const* d_in, const int* in_sizes, int n_in,
                              void* d_out, int out_size, void* d_ws, size_t ws_size,
                              hipStream_t stream) {
    const float* x = (const float*)d_in[0];
    size_t SZ = (size_t)BB * NN * CC;          // elements
    size_t BN = (size_t)BB * NN;
    u16* XT = (u16*)d_ws;
    u16* XN = XT + SZ;
    u16* P1 = XN + SZ;
    float* norms = (float*)(P1 + SZ);
    float* l0g   = norms + BN;
    float* l1g   = l0g + BN;
    float* normp = l1g + BN;                   // 8 * B * N floats
    int*   maxn  = (int*)(normp + 8 * BN);
    size_t needed = 3 * SZ * 2 + 3 * BN * 4 + 8 * BN * 4 + 64;
    int split = (ws_size >= needed) ? 1 : 0;
    float* out = (float*)d_out;
    if (!split) {   // fallback layout without P1
        norms = (float*)(XN + SZ);
        l0g = norms + BN;
        l1g = l0g;
        normp = l1g + BN;
        maxn = (int*)(normp + 8 * BN);
    }

    prep_kernel<<<2048, 256, 0, stream>>>(x, XT, XN, normp);
    nred_kernel<<<BB, 1024, 0, stream>>>(normp, norms, maxn);
    if (split) {
        flash_kernel<<<512, 256, 0, stream>>>(XT, XN, norms, maxn, out, P1, l0g, l1g, 1);
        combine_kernel<<<(BB * CC * NN / 4) / 256, 256, 0, stream>>>(out, P1, l0g, l1g);
    } else {
        flash_kernel<<<256, 256, 0, stream>>>(XT, XN, norms, maxn, out, P1, l0g, l1g, 0);
    }
}